// Round 5
// baseline (8386.817 us; speedup 1.0000x reference)
//
#include <hip/hip_runtime.h>
#include <hip/hip_bf16.h>
#include <cstdint>
#include <cstddef>

#define B_ 128
#define T_ 100
#define D_ 2048
#define H_ 1024
#define O_ 20

// ---------------------------------------------------------------------------
// prep: W2oT[h][o] = Wh2o[o][h]; zero nbr accumulators and bg counters.
// ---------------------------------------------------------------------------
__global__ __launch_bounds__(256) void prep_kernel(const float* __restrict__ Wh2o,
                                                   float* __restrict__ W2oT,
                                                   float* __restrict__ nbr,
                                                   int* __restrict__ g_cnt)
{
    int i = blockIdx.x * 256 + threadIdx.x;
    if (i < H_ * O_) {
        int hh = i / O_;
        int oo = i - hh * O_;
        W2oT[i] = Wh2o[oo * H_ + hh];
    }
    if (i < T_) nbr[i] = 0.0f;
    if (i < 16) g_cnt[i] = 0;
}

// ---------------------------------------------------------------------------
// transpose Wh2h[h][j] -> WT[j][h]
// ---------------------------------------------------------------------------
__global__ __launch_bounds__(256) void transpose_kernel(const float* __restrict__ A,
                                                        float* __restrict__ AT)
{
    __shared__ float tile[32][33];
    int bx = blockIdx.x * 32, by = blockIdx.y * 32;
    int tx = threadIdx.x, ty = threadIdx.y;  // block (32,8)
#pragma unroll
    for (int i = 0; i < 32; i += 8)
        tile[ty + i][tx] = A[(size_t)(by + ty + i) * H_ + bx + tx];
    __syncthreads();
#pragma unroll
    for (int i = 0; i < 32; i += 8)
        AT[(size_t)(bx + ty + i) * H_ + by + tx] = tile[tx][ty + i];
}

// ---------------------------------------------------------------------------
// Xi = X @ Wi2h^T + (bi2h + bh2h).  128x128x16 tile, 256 threads, 8x8 micro.
// ---------------------------------------------------------------------------
__global__ __launch_bounds__(256) void gemm_xi_kernel(
    const float* __restrict__ X,     // [B*T, D]
    const float* __restrict__ W,     // [H, D]
    const float* __restrict__ bi2h,
    const float* __restrict__ bh2h,
    float* __restrict__ Xi)          // [B*T, H]
{
    constexpr int BM = 128, BN = 128, BK = 16;
    __shared__ float As[BK][BM + 4];
    __shared__ float Bs[BK][BN + 4];
    const int tid = threadIdx.x;
    const int m0 = blockIdx.x * BM;
    const int n0 = blockIdx.y * BN;
    const int wave = tid >> 6;
    const int lane = tid & 63;
    const int tm = ((wave >> 1) << 3) | (lane >> 3);   // 0..15
    const int tn = ((wave & 1) << 3) | (lane & 7);     // 0..15
    const int ldr = tid >> 2;          // 0..63
    const int ldc = (tid & 3) << 2;    // 0,4,8,12

    float acc[8][8];
#pragma unroll
    for (int i = 0; i < 8; ++i)
#pragma unroll
        for (int j = 0; j < 8; ++j) acc[i][j] = 0.0f;

    for (int k0 = 0; k0 < D_; k0 += BK) {
#pragma unroll
        for (int p = 0; p < 2; ++p) {
            int r = ldr + p * 64;
            float4 v = *(const float4*)(X + (size_t)(m0 + r) * D_ + k0 + ldc);
            As[ldc + 0][r] = v.x; As[ldc + 1][r] = v.y;
            As[ldc + 2][r] = v.z; As[ldc + 3][r] = v.w;
        }
#pragma unroll
        for (int p = 0; p < 2; ++p) {
            int r = ldr + p * 64;
            float4 v = *(const float4*)(W + (size_t)(n0 + r) * D_ + k0 + ldc);
            Bs[ldc + 0][r] = v.x; Bs[ldc + 1][r] = v.y;
            Bs[ldc + 2][r] = v.z; Bs[ldc + 3][r] = v.w;
        }
        __syncthreads();
#pragma unroll
        for (int k = 0; k < BK; ++k) {
            float4 A0 = *(const float4*)&As[k][tm * 8];
            float4 A1 = *(const float4*)&As[k][tm * 8 + 4];
            float4 B0 = *(const float4*)&Bs[k][tn * 8];
            float4 B1 = *(const float4*)&Bs[k][tn * 8 + 4];
            float a[8] = {A0.x, A0.y, A0.z, A0.w, A1.x, A1.y, A1.z, A1.w};
            float bb[8] = {B0.x, B0.y, B0.z, B0.w, B1.x, B1.y, B1.z, B1.w};
#pragma unroll
            for (int i = 0; i < 8; ++i)
#pragma unroll
                for (int j = 0; j < 8; ++j) acc[i][j] += a[i] * bb[j];
        }
        __syncthreads();
    }

    float bsum[8];
#pragma unroll
    for (int j = 0; j < 8; ++j) {
        int n = n0 + tn * 8 + j;
        bsum[j] = bi2h[n] + bh2h[n];
    }
#pragma unroll
    for (int i = 0; i < 8; ++i) {
        size_t row = (size_t)(m0 + tm * 8 + i);
        float4 o0 = {acc[i][0] + bsum[0], acc[i][1] + bsum[1],
                     acc[i][2] + bsum[2], acc[i][3] + bsum[3]};
        float4 o1 = {acc[i][4] + bsum[4], acc[i][5] + bsum[5],
                     acc[i][6] + bsum[6], acc[i][7] + bsum[7]};
        *(float4*)(Xi + row * H_ + n0 + tn * 8)     = o0;
        *(float4*)(Xi + row * H_ + n0 + tn * 8 + 4) = o1;
    }
}

// ---------------------------------------------------------------------------
// phase2 v5 — dense multi-batch recurrence with TRUE read sharing.
// 512 wgs x 320 threads: wg (bg,cg) owns 8 batches x 32 columns. Gather:
// waves 0..3 each cover 256 rows; lane=(rowslot,colq) reads one float4 of a
// row slice ONCE (lanes 0..7 = 128B contiguous, 8 rows in flight) and FMAs
// it into 8 per-batch float4 accumulators gated by s in {0,1} (fmaf(0,w,a)
// ==a exactly -> numerics == ordered sum; validated absmax 0.0 in R1/R2/R4).
// Spike gates precomputed once/step into s_f[row][8] (2 conflict-free
// ds_read_b128/iter). Butterfly-reduce across rowslot lanes, then LDS.
// XCD locality: cg=(blk&7)*4+((blk>>3)&3) -> 4x128KB WT slice per XCD.
// Sync: R4's per-bg counter + double-buffered mask/o-partial exchange.
// Owner wg (cg==bg) wave 4 does o-LIF + nbr one step behind.
// ---------------------------------------------------------------------------
__global__ __launch_bounds__(320) void phase2_kernel(
    const float* __restrict__ Xi,      // [B*T, H]
    const float* __restrict__ WT,      // [j*H + h]
    const float* __restrict__ W2oT,    // [h*O + o]
    const float* __restrict__ bh2o,
    const float* __restrict__ thr_h_g,
    const float* __restrict__ thr_o_g,
    const float* __restrict__ hm0,
    const float* __restrict__ hs0,
    const float* __restrict__ om0,
    unsigned int* __restrict__ g_mask32,  // [2 buf][128 batch][32 cg]
    float* __restrict__ g_opart,          // [2 buf][128 batch][32 cg][20]
    int* __restrict__ g_cnt,              // [16 bg]
    ulonglong2* __restrict__ spk,         // [B*H]
    float* __restrict__ osum_out,         // [B,O]
    float* __restrict__ nbr_acc)          // [T] pre-zeroed
{
    const int blk = blockIdx.x;
    const int q = blk >> 3;
    const int cg = (blk & 7) * 4 + (q & 3);    // 0..31, 4 per XCD
    const int bg = q >> 2;                     // 0..15
    const int b0 = bg * 8;
    const int c0 = cg * 32;
    const int tid = threadIdx.x;
    const int lane = tid & 63;
    const int wv = tid >> 6;                   // 0..4
    const bool owner = (cg == bg);

    __shared__ float s_f[H_ * 8];              // 32KB  [row][b] spike gates
    __shared__ float4 s_red[4][8][10];         // [wave][b][colq] (+pad)
    __shared__ unsigned int s_mask32[256];     // [b][w32]
    __shared__ float s_om[160], s_osum[160];
    __shared__ float s_bo[O_], s_tho[O_];

    float hm = 0.0f, thr = 1.0f;
    if (tid < 256) {
        int b = tid >> 5, hoff = tid & 31;
        hm = hm0[(size_t)(b0 + b) * H_ + c0 + hoff];
        thr = thr_h_g[c0 + hoff];
    }
    if (tid < 160) {
        s_om[tid] = om0[(b0 + tid / O_) * O_ + tid % O_];
        s_osum[tid] = 0.0f;
    }
    if (tid < O_) { s_bo[tid] = bh2o[tid]; s_tho[tid] = thr_o_g[tid]; }

    // initial masks from hs0
    for (int idx = tid; idx < 256; idx += 320) {
        int b = idx >> 5, w32 = idx & 31;
        const float* base = hs0 + (size_t)(b0 + b) * H_ + w32 * 32;
        unsigned int mw = 0;
#pragma unroll
        for (int k = 0; k < 32; ++k)
            mw |= (base[k] > 0.5f ? 1u : 0u) << k;
        s_mask32[idx] = mw;
    }
    __syncthreads();

    // wave-4 (o-layer) lane->(b,o) assignment
    int vb[3], vo[3];
#pragma unroll
    for (int p = 0; p < 3; ++p) {
        int idx = p * 64 + lane;
        vb[p] = idx / O_;
        vo[p] = idx - vb[p] * O_;
    }

    const int rowslot = lane >> 3;   // 0..7
    const int colq = lane & 7;       // float4 within 32 cols
    unsigned long long bits0 = 0, bits1 = 0;

    for (int t = 0; t <= T_; ++t) {
        const bool full = (t < T_);

        float xi = 0.0f;
        if (full && tid < 256)
            xi = Xi[((size_t)(b0 + (tid >> 5)) * T_ + t) * H_ + c0 + (tid & 31)];

        if (t > 0 && tid == 0) {
            while (__hip_atomic_load(g_cnt + bg, __ATOMIC_ACQUIRE,
                                     __HIP_MEMORY_SCOPE_AGENT) < 32 * t)
                __builtin_amdgcn_s_sleep(2);
        }
        __syncthreads();                       // S1
        if (t > 0 && tid < 256) {
            s_mask32[tid] = __hip_atomic_load(
                g_mask32 + ((t - 1) & 1) * 4096 + (b0 + (tid >> 5)) * 32 + (tid & 31),
                __ATOMIC_RELAXED, __HIP_MEMORY_SCOPE_AGENT);
        }
        __syncthreads();                       // S2

        // precompute spike gate floats s_f[row][b] (all 320 threads)
        if (full) {
            for (int idx = tid; idx < H_ * 8; idx += 320) {
                int row = idx >> 3, b = idx & 7;
                s_f[idx] = (float)((s_mask32[b * 32 + (row >> 5)] >> (row & 31)) & 1u);
            }
        }
        __syncthreads();                       // S2b

        if (wv < 4) {
            if (full) {
                // ---- dense shared gather: wave wv covers rows wv*256..+255
                const float4* wp =
                    (const float4*)(WT + (size_t)(wv * 256 + rowslot) * H_ + c0) + colq;
                float4 a0 = {0,0,0,0}, a1 = {0,0,0,0}, a2 = {0,0,0,0}, a3 = {0,0,0,0};
                float4 a4 = {0,0,0,0}, a5 = {0,0,0,0}, a6 = {0,0,0,0}, a7 = {0,0,0,0};
                const float* sfp = s_f + (size_t)(wv * 256 + rowslot) * 8;
#pragma unroll 4
                for (int i = 0; i < 32; ++i) {
                    float4 w = wp[(size_t)i * 2048];
                    float4 sA = *(const float4*)(sfp + (size_t)i * 64);
                    float4 sB = *(const float4*)(sfp + (size_t)i * 64 + 4);
                    a0.x = fmaf(sA.x, w.x, a0.x); a0.y = fmaf(sA.x, w.y, a0.y);
                    a0.z = fmaf(sA.x, w.z, a0.z); a0.w = fmaf(sA.x, w.w, a0.w);
                    a1.x = fmaf(sA.y, w.x, a1.x); a1.y = fmaf(sA.y, w.y, a1.y);
                    a1.z = fmaf(sA.y, w.z, a1.z); a1.w = fmaf(sA.y, w.w, a1.w);
                    a2.x = fmaf(sA.z, w.x, a2.x); a2.y = fmaf(sA.z, w.y, a2.y);
                    a2.z = fmaf(sA.z, w.z, a2.z); a2.w = fmaf(sA.z, w.w, a2.w);
                    a3.x = fmaf(sA.w, w.x, a3.x); a3.y = fmaf(sA.w, w.y, a3.y);
                    a3.z = fmaf(sA.w, w.z, a3.z); a3.w = fmaf(sA.w, w.w, a3.w);
                    a4.x = fmaf(sB.x, w.x, a4.x); a4.y = fmaf(sB.x, w.y, a4.y);
                    a4.z = fmaf(sB.x, w.z, a4.z); a4.w = fmaf(sB.x, w.w, a4.w);
                    a5.x = fmaf(sB.y, w.x, a5.x); a5.y = fmaf(sB.y, w.y, a5.y);
                    a5.z = fmaf(sB.y, w.z, a5.z); a5.w = fmaf(sB.y, w.w, a5.w);
                    a6.x = fmaf(sB.z, w.x, a6.x); a6.y = fmaf(sB.z, w.y, a6.y);
                    a6.z = fmaf(sB.z, w.z, a6.z); a6.w = fmaf(sB.z, w.w, a6.w);
                    a7.x = fmaf(sB.w, w.x, a7.x); a7.y = fmaf(sB.w, w.y, a7.y);
                    a7.z = fmaf(sB.w, w.z, a7.z); a7.w = fmaf(sB.w, w.w, a7.w);
                }
                // butterfly-reduce across rowslot (lane bits 3,4,5)
                float4 acc[8] = {a0, a1, a2, a3, a4, a5, a6, a7};
#pragma unroll
                for (int d = 8; d < 64; d <<= 1) {
#pragma unroll
                    for (int b = 0; b < 8; ++b) {
                        acc[b].x += __shfl_xor(acc[b].x, d);
                        acc[b].y += __shfl_xor(acc[b].y, d);
                        acc[b].z += __shfl_xor(acc[b].z, d);
                        acc[b].w += __shfl_xor(acc[b].w, d);
                    }
                }
                // all lanes hold full sums; lane writes batch=rowslot
                s_red[wv][rowslot][colq] = acc[rowslot];
            }
        } else if (owner && t > 0) {
            // ---- wave 4 of owner wg: o-LIF(t-1) + nbr(t-1)
            const int bufp = (t - 1) & 1;
            float ospsum = 0.0f;
#pragma unroll
            for (int p = 0; p < 3; ++p) {
                int idx = p * 64 + lane;
                if (idx < 160) {
                    const float* gp =
                        g_opart + bufp * 81920 + ((b0 + vb[p]) * 32) * O_ + vo[p];
                    float oin = s_bo[vo[p]];
#pragma unroll
                    for (int c = 0; c < 32; ++c)
                        oin += __hip_atomic_load(gp + c * O_, __ATOMIC_RELAXED,
                                                 __HIP_MEMORY_SCOPE_AGENT);
                    float om = s_om[idx] + oin;
                    float osp = ((om - s_tho[vo[p]]) > 0.0f) ? 1.0f : 0.0f;
                    if (osp > 0.5f) om = 0.0f;
                    if (om < -s_tho[vo[p]]) om = -s_tho[vo[p]];
                    s_om[idx] = om;
                    s_osum[idx] += osp;
                    ospsum += osp;
                }
            }
            int hid = 0;
#pragma unroll
            for (int k = 0; k < 4; ++k) hid += __popc(s_mask32[lane * 4 + k]);
            float tot = ospsum + (float)hid;
            tot += __shfl_xor(tot, 1);  tot += __shfl_xor(tot, 2);
            tot += __shfl_xor(tot, 4);  tot += __shfl_xor(tot, 8);
            tot += __shfl_xor(tot, 16); tot += __shfl_xor(tot, 32);
            if (lane == 0) atomicAdd(&nbr_acc[t - 1], tot);  // exact ints
        }
        __syncthreads();                       // S3

        if (full && tid < 256) {
            const int b = tid >> 5, hoff = tid & 31;
            const int cq = hoff >> 2, comp = hoff & 3;
            float val = ((const float*)&s_red[0][b][cq])[comp] +
                        ((const float*)&s_red[1][b][cq])[comp] +
                        ((const float*)&s_red[2][b][cq])[comp] +
                        ((const float*)&s_red[3][b][cq])[comp];
            hm += xi + val;
            bool spb = (hm - thr) > 0.0f;      // strict >
            if (spb) hm = 0.0f;
            if (hm < -thr) hm = -thr;
            if (spb) { if (t < 64) bits0 |= 1ull << t; else bits1 |= 1ull << (t - 64); }

            unsigned long long bal = __ballot(spb);
            const int wb = tid >> 6;           // wave holds batches 2wb, 2wb+1
            const int buf = t & 1;
            if (lane == 0)
                __hip_atomic_store(g_mask32 + buf * 4096 + (b0 + wb * 2) * 32 + cg,
                                   (unsigned int)bal, __ATOMIC_RELAXED,
                                   __HIP_MEMORY_SCOPE_AGENT);
            if (lane == 32)
                __hip_atomic_store(g_mask32 + buf * 4096 + (b0 + wb * 2 + 1) * 32 + cg,
                                   (unsigned int)(bal >> 32), __ATOMIC_RELAXED,
                                   __HIP_MEMORY_SCOPE_AGENT);
            const int o = lane & 31;
            if (o < O_) {
                unsigned int mm = (lane < 32) ? (unsigned int)bal
                                              : (unsigned int)(bal >> 32);
                const int ob = b0 + wb * 2 + (lane >= 32 ? 1 : 0);
                float op = 0.0f;
                while (mm) {
                    int j = __builtin_ctz(mm);
                    mm &= mm - 1;
                    op += W2oT[(c0 + j) * O_ + o];
                }
                __hip_atomic_store(g_opart + buf * 81920 + (ob * 32 + cg) * O_ + o,
                                   op, __ATOMIC_RELAXED, __HIP_MEMORY_SCOPE_AGENT);
            }
        }
        __syncthreads();                       // S4
        if (full && tid == 0)
            __hip_atomic_fetch_add(g_cnt + bg, 1, __ATOMIC_RELEASE,
                                   __HIP_MEMORY_SCOPE_AGENT);
    }

    if (tid < 256) {
        int b = tid >> 5, hoff = tid & 31;
        ulonglong2 vv; vv.x = bits0; vv.y = bits1;
        spk[(size_t)(b0 + b) * H_ + c0 + hoff] = vv;
    }
    if (owner && tid < 160)
        osum_out[(b0 + tid / O_) * O_ + tid % O_] = s_osum[tid];
}

// ---------------------------------------------------------------------------
// sliding-window mean of spike bitmasks
// ---------------------------------------------------------------------------
__global__ __launch_bounds__(256) void filt_kernel(const ulonglong2* __restrict__ spk,
                                                   float* __restrict__ outf)
{
    int i = blockIdx.x * 256 + threadIdx.x;
    ulonglong2 v = spk[i];
    float* o = outf + (size_t)i * 91;
    int s = __popcll(v.x & 0x3FFull);
    o[0] = (float)s * 0.1f;
#pragma unroll 1
    for (int tau = 1; tau <= 90; ++tau) {
        int ta = tau + 9, tsb = tau - 1;
        int add = (ta < 64) ? (int)((v.x >> ta) & 1ull) : (int)((v.y >> (ta - 64)) & 1ull);
        int sub = (tsb < 64) ? (int)((v.x >> tsb) & 1ull) : (int)((v.y >> (tsb - 64)) & 1ull);
        s += add - sub;
        o[tau] = (float)s * 0.1f;
    }
}

// ---------------------------------------------------------------------------
// predictions / loss / nbr scaling
// ---------------------------------------------------------------------------
__global__ __launch_bounds__(256) void final_kernel(const float* __restrict__ osum,
                                                    const int* __restrict__ labels,
                                                    float* __restrict__ dout)
{
    __shared__ float s_loss[B_];
    int tid = threadIdx.x;
    if (tid < B_) {
        int b = tid;
        float v[O_];
#pragma unroll
        for (int o = 0; o < O_; ++o) v[o] = osum[b * O_ + o];
        float mv = v[0];
        int am = 0;
#pragma unroll
        for (int o = 1; o < O_; ++o)
            if (v[o] > mv) { mv = v[o]; am = o; }   // strict >: first max wins
        float se = 0.0f;
#pragma unroll
        for (int o = 0; o < O_; ++o) se += expf(v[o] - mv);
        float lse = mv + logf(se);
        dout[b] = (float)am;
        s_loss[b] = v[labels[b]] - lse;
    }
    if (tid >= 128 && tid < 128 + T_) {
        dout[129 + (tid - 128)] *= (1.0f / (float)B_);
    }
    __syncthreads();
    if (tid == 0) {
        float s = 0.0f;
        for (int b = 0; b < B_; ++b) s += s_loss[b];
        dout[128] = -s / (float)B_;
    }
}

// ---------------------------------------------------------------------------
extern "C" void kernel_launch(void* const* d_in, const int* in_sizes, int n_in,
                              void* d_out, int out_size, void* d_ws, size_t ws_size,
                              hipStream_t stream)
{
    const float* input  = (const float*)d_in[0];
    const int*   labels = (const int*)d_in[1];
    const float* hm0    = (const float*)d_in[2];
    const float* hs0    = (const float*)d_in[3];
    const float* om0    = (const float*)d_in[4];
    const float* Wi2h   = (const float*)d_in[6];
    const float* bi2h   = (const float*)d_in[7];
    const float* Wh2h   = (const float*)d_in[8];
    const float* bh2h   = (const float*)d_in[9];
    const float* Wh2o   = (const float*)d_in[10];
    const float* bh2o   = (const float*)d_in[11];
    const float* thr_h  = (const float*)d_in[12];
    const float* thr_o  = (const float*)d_in[13];

    float* out  = (float*)d_out;
    float* nbr  = out + 129;
    float* filt = out + 229;

    char* ws = (char*)d_ws;
    float*        Xi     = (float*)(ws);                 // 52,428,800
    float*        WT     = (float*)(ws + 52428800);      //  4,194,304
    float*        W2oT   = (float*)(ws + 56623104);      //     81,920
    ulonglong2*   spk    = (ulonglong2*)(ws + 56705024); //  2,097,152
    float*        osum   = (float*)(ws + 58802176);      //     10,240
    unsigned int* g_mask32 = (unsigned int*)(ws + 58812416); // 32,768
    float*        g_opart  = (float*)(ws + 58845184);    //    655,360
    int*          g_cnt    = (int*)(ws + 59500544);      //         64

    prep_kernel<<<80, 256, 0, stream>>>(Wh2o, W2oT, nbr, g_cnt);
    transpose_kernel<<<dim3(32, 32), dim3(32, 8), 0, stream>>>(Wh2h, WT);
    gemm_xi_kernel<<<dim3(100, 8), 256, 0, stream>>>(input, Wi2h, bi2h, bh2h, Xi);
    phase2_kernel<<<512, 320, 0, stream>>>(Xi, WT, W2oT, bh2o, thr_h, thr_o,
                                           hm0, hs0, om0, g_mask32, g_opart, g_cnt,
                                           spk, osum, nbr);
    filt_kernel<<<512, 256, 0, stream>>>(spk, filt);
    final_kernel<<<1, 256, 0, stream>>>(osum, labels, out);
}

// Round 6
// 6047.587 us; speedup vs baseline: 1.3868x; 1.3868x over previous
//
#include <hip/hip_runtime.h>
#include <hip/hip_bf16.h>
#include <cstdint>
#include <cstddef>

#define B_ 128
#define T_ 100
#define D_ 2048
#define H_ 1024
#define O_ 20

// ---------------------------------------------------------------------------
// prep: W2oT[h][o] = Wh2o[o][h]; zero nbr accumulators and bg counters.
// ---------------------------------------------------------------------------
__global__ __launch_bounds__(256) void prep_kernel(const float* __restrict__ Wh2o,
                                                   float* __restrict__ W2oT,
                                                   float* __restrict__ nbr,
                                                   int* __restrict__ g_cnt)
{
    int i = blockIdx.x * 256 + threadIdx.x;
    if (i < H_ * O_) {
        int hh = i / O_;
        int oo = i - hh * O_;
        W2oT[i] = Wh2o[oo * H_ + hh];
    }
    if (i < T_) nbr[i] = 0.0f;
    if (i < 16) g_cnt[i] = 0;
}

// ---------------------------------------------------------------------------
// transpose Wh2h[h][j] -> WT[j][h]
// ---------------------------------------------------------------------------
__global__ __launch_bounds__(256) void transpose_kernel(const float* __restrict__ A,
                                                        float* __restrict__ AT)
{
    __shared__ float tile[32][33];
    int bx = blockIdx.x * 32, by = blockIdx.y * 32;
    int tx = threadIdx.x, ty = threadIdx.y;  // block (32,8)
#pragma unroll
    for (int i = 0; i < 32; i += 8)
        tile[ty + i][tx] = A[(size_t)(by + ty + i) * H_ + bx + tx];
    __syncthreads();
#pragma unroll
    for (int i = 0; i < 32; i += 8)
        AT[(size_t)(bx + ty + i) * H_ + by + tx] = tile[tx][ty + i];
}

// ---------------------------------------------------------------------------
// Xi = X @ Wi2h^T + (bi2h + bh2h).  128x128x16 tile, 256 threads, 8x8 micro.
// ---------------------------------------------------------------------------
__global__ __launch_bounds__(256) void gemm_xi_kernel(
    const float* __restrict__ X,     // [B*T, D]
    const float* __restrict__ W,     // [H, D]
    const float* __restrict__ bi2h,
    const float* __restrict__ bh2h,
    float* __restrict__ Xi)          // [B*T, H]
{
    constexpr int BM = 128, BN = 128, BK = 16;
    __shared__ float As[BK][BM + 4];
    __shared__ float Bs[BK][BN + 4];
    const int tid = threadIdx.x;
    const int m0 = blockIdx.x * BM;
    const int n0 = blockIdx.y * BN;
    const int wave = tid >> 6;
    const int lane = tid & 63;
    const int tm = ((wave >> 1) << 3) | (lane >> 3);   // 0..15
    const int tn = ((wave & 1) << 3) | (lane & 7);     // 0..15
    const int ldr = tid >> 2;          // 0..63
    const int ldc = (tid & 3) << 2;    // 0,4,8,12

    float acc[8][8];
#pragma unroll
    for (int i = 0; i < 8; ++i)
#pragma unroll
        for (int j = 0; j < 8; ++j) acc[i][j] = 0.0f;

    for (int k0 = 0; k0 < D_; k0 += BK) {
#pragma unroll
        for (int p = 0; p < 2; ++p) {
            int r = ldr + p * 64;
            float4 v = *(const float4*)(X + (size_t)(m0 + r) * D_ + k0 + ldc);
            As[ldc + 0][r] = v.x; As[ldc + 1][r] = v.y;
            As[ldc + 2][r] = v.z; As[ldc + 3][r] = v.w;
        }
#pragma unroll
        for (int p = 0; p < 2; ++p) {
            int r = ldr + p * 64;
            float4 v = *(const float4*)(W + (size_t)(n0 + r) * D_ + k0 + ldc);
            Bs[ldc + 0][r] = v.x; Bs[ldc + 1][r] = v.y;
            Bs[ldc + 2][r] = v.z; Bs[ldc + 3][r] = v.w;
        }
        __syncthreads();
#pragma unroll
        for (int k = 0; k < BK; ++k) {
            float4 A0 = *(const float4*)&As[k][tm * 8];
            float4 A1 = *(const float4*)&As[k][tm * 8 + 4];
            float4 B0 = *(const float4*)&Bs[k][tn * 8];
            float4 B1 = *(const float4*)&Bs[k][tn * 8 + 4];
            float a[8] = {A0.x, A0.y, A0.z, A0.w, A1.x, A1.y, A1.z, A1.w};
            float bb[8] = {B0.x, B0.y, B0.z, B0.w, B1.x, B1.y, B1.z, B1.w};
#pragma unroll
            for (int i = 0; i < 8; ++i)
#pragma unroll
                for (int j = 0; j < 8; ++j) acc[i][j] += a[i] * bb[j];
        }
        __syncthreads();
    }

    float bsum[8];
#pragma unroll
    for (int j = 0; j < 8; ++j) {
        int n = n0 + tn * 8 + j;
        bsum[j] = bi2h[n] + bh2h[n];
    }
#pragma unroll
    for (int i = 0; i < 8; ++i) {
        size_t row = (size_t)(m0 + tm * 8 + i);
        float4 o0 = {acc[i][0] + bsum[0], acc[i][1] + bsum[1],
                     acc[i][2] + bsum[2], acc[i][3] + bsum[3]};
        float4 o1 = {acc[i][4] + bsum[4], acc[i][5] + bsum[5],
                     acc[i][6] + bsum[6], acc[i][7] + bsum[7]};
        *(float4*)(Xi + row * H_ + n0 + tn * 8)     = o0;
        *(float4*)(Xi + row * H_ + n0 + tn * 8 + 4) = o1;
    }
}

// ---------------------------------------------------------------------------
// phase2 v6 — dense multi-batch, spill-free shared-read gather.
// 512 wgs x 320 threads: wg (bg,cg) owns 8 batches x 32 columns.
// Waves 0..3: lane=(rowslot 0..7, colq 0..7); wave wv covers rows
// wv*256 + i*8 + rowslot, i=0..31 -> 32 coalesced float4 WT loads per lane
// per step, each shared across 8 batches via fmaf(gate, w, acc) with gate
// in {0,1} (fmaf(0,w,a)==a exactly -> ordered-sum numerics, validated
// absmax 0.0 in R1/R2/R4/R5). Gate bits: word index wv*8+(i>>2) is
// wave-uniform (8i+rowslot<=255 => >>5 drops rowslot), so masks reload from
// LDS broadcast every 4 iters; bit = 8*(i&3)+rowslot per lane.
// Accumulators: 8 NAMED float4s (no arrays -> no scratch spill; R5 lesson).
// Partials -> s_part[4][8][8][8] float4, reduced by LIF threads (32 adds).
// XCD locality: cg=(blk&7)*4+((blk>>3)&3) -> 512KB WT slice/XCD (R4-proven
// FETCH ~57MB). Sync: R4's per-bg counter + double-buffered mask/o-partial
// exchange. Owner wg (cg==bg) wave 4 does o-LIF + nbr one step behind.
// ---------------------------------------------------------------------------
__global__ __launch_bounds__(320) void phase2_kernel(
    const float* __restrict__ Xi,      // [B*T, H]
    const float* __restrict__ WT,      // [j*H + h]
    const float* __restrict__ W2oT,    // [h*O + o]
    const float* __restrict__ bh2o,
    const float* __restrict__ thr_h_g,
    const float* __restrict__ thr_o_g,
    const float* __restrict__ hm0,
    const float* __restrict__ hs0,
    const float* __restrict__ om0,
    unsigned int* __restrict__ g_mask32,  // [2 buf][128 batch][32 cg]
    float* __restrict__ g_opart,          // [2 buf][128 batch][32 cg][20]
    int* __restrict__ g_cnt,              // [16 bg]
    ulonglong2* __restrict__ spk,         // [B*H]
    float* __restrict__ osum_out,         // [B,O]
    float* __restrict__ nbr_acc)          // [T] pre-zeroed
{
    const int blk = blockIdx.x;
    const int q = blk >> 3;
    const int cg = (blk & 7) * 4 + (q & 3);    // 0..31, 4 per XCD
    const int bg = q >> 2;                     // 0..15
    const int b0 = bg * 8;
    const int c0 = cg * 32;
    const int tid = threadIdx.x;
    const int lane = tid & 63;
    const int wv = tid >> 6;                   // 0..4
    const bool owner = (cg == bg);

    __shared__ float4 s_part[4 * 8 * 8 * 8];   // 32KB [wv][rowslot][b][colq]
    __shared__ unsigned int s_mask32[256];     // [b][w32]
    __shared__ float s_om[160], s_osum[160];
    __shared__ float s_bo[O_], s_tho[O_];

    float hm = 0.0f, thr = 1.0f;
    if (tid < 256) {
        int b = tid >> 5, hoff = tid & 31;
        hm = hm0[(size_t)(b0 + b) * H_ + c0 + hoff];
        thr = thr_h_g[c0 + hoff];
    }
    if (tid < 160) {
        s_om[tid] = om0[(b0 + tid / O_) * O_ + tid % O_];
        s_osum[tid] = 0.0f;
    }
    if (tid < O_) { s_bo[tid] = bh2o[tid]; s_tho[tid] = thr_o_g[tid]; }

    // initial masks from hs0
    for (int idx = tid; idx < 256; idx += 320) {
        int b = idx >> 5, w32 = idx & 31;
        const float* base = hs0 + (size_t)(b0 + b) * H_ + w32 * 32;
        unsigned int mw = 0;
#pragma unroll
        for (int k = 0; k < 32; ++k)
            mw |= (base[k] > 0.5f ? 1u : 0u) << k;
        s_mask32[idx] = mw;
    }
    __syncthreads();

    // wave-4 (o-layer) lane->(b,o) assignment
    int vb[3], vo[3];
#pragma unroll
    for (int p = 0; p < 3; ++p) {
        int idx = p * 64 + lane;
        vb[p] = idx / O_;
        vo[p] = idx - vb[p] * O_;
    }

    const int rowslot = lane >> 3;   // 0..7
    const int colq = lane & 7;       // float4 within 32 cols
    // WT base for this lane: row (wv*256 + rowslot), float4 col cg*8+colq
    const float4* __restrict__ wp =
        (const float4*)WT + (((size_t)(wv & 3) * 256 + rowslot) << 8) + (cg << 3) + colq;
    const int pbase = (((wv & 3) * 8 + rowslot) * 8) * 8 + colq;  // b stride 8

    unsigned long long bits0 = 0, bits1 = 0;

    for (int t = 0; t <= T_; ++t) {
        const bool full = (t < T_);

        float xi = 0.0f;
        if (full && tid < 256)
            xi = Xi[((size_t)(b0 + (tid >> 5)) * T_ + t) * H_ + c0 + (tid & 31)];

        if (t > 0 && tid == 0) {
            while (__hip_atomic_load(g_cnt + bg, __ATOMIC_ACQUIRE,
                                     __HIP_MEMORY_SCOPE_AGENT) < 32 * t)
                __builtin_amdgcn_s_sleep(2);
        }
        __syncthreads();                       // S1
        if (t > 0 && tid < 256) {
            s_mask32[tid] = __hip_atomic_load(
                g_mask32 + ((t - 1) & 1) * 4096 + (b0 + (tid >> 5)) * 32 + (tid & 31),
                __ATOMIC_RELAXED, __HIP_MEMORY_SCOPE_AGENT);
        }
        __syncthreads();                       // S2

        if (wv < 4) {
            if (full) {
                float4 a0 = {0,0,0,0}, a1 = {0,0,0,0}, a2 = {0,0,0,0}, a3 = {0,0,0,0};
                float4 a4 = {0,0,0,0}, a5 = {0,0,0,0}, a6 = {0,0,0,0}, a7 = {0,0,0,0};
#pragma unroll
                for (int iw = 0; iw < 8; ++iw) {       // word groups (4 iters each)
                    const int wi = wv * 8 + iw;
                    const unsigned int m0b = s_mask32[0 * 32 + wi];
                    const unsigned int m1b = s_mask32[1 * 32 + wi];
                    const unsigned int m2b = s_mask32[2 * 32 + wi];
                    const unsigned int m3b = s_mask32[3 * 32 + wi];
                    const unsigned int m4b = s_mask32[4 * 32 + wi];
                    const unsigned int m5b = s_mask32[5 * 32 + wi];
                    const unsigned int m6b = s_mask32[6 * 32 + wi];
                    const unsigned int m7b = s_mask32[7 * 32 + wi];
#pragma unroll
                    for (int ii = 0; ii < 4; ++ii) {
                        const int i = iw * 4 + ii;
                        const float4 w = wp[(size_t)i * 2048];
                        const int bit = (ii << 3) + rowslot;
                        const float g0 = (float)((m0b >> bit) & 1u);
                        const float g1 = (float)((m1b >> bit) & 1u);
                        const float g2 = (float)((m2b >> bit) & 1u);
                        const float g3 = (float)((m3b >> bit) & 1u);
                        const float g4 = (float)((m4b >> bit) & 1u);
                        const float g5 = (float)((m5b >> bit) & 1u);
                        const float g6 = (float)((m6b >> bit) & 1u);
                        const float g7 = (float)((m7b >> bit) & 1u);
                        a0.x = fmaf(g0, w.x, a0.x); a0.y = fmaf(g0, w.y, a0.y);
                        a0.z = fmaf(g0, w.z, a0.z); a0.w = fmaf(g0, w.w, a0.w);
                        a1.x = fmaf(g1, w.x, a1.x); a1.y = fmaf(g1, w.y, a1.y);
                        a1.z = fmaf(g1, w.z, a1.z); a1.w = fmaf(g1, w.w, a1.w);
                        a2.x = fmaf(g2, w.x, a2.x); a2.y = fmaf(g2, w.y, a2.y);
                        a2.z = fmaf(g2, w.z, a2.z); a2.w = fmaf(g2, w.w, a2.w);
                        a3.x = fmaf(g3, w.x, a3.x); a3.y = fmaf(g3, w.y, a3.y);
                        a3.z = fmaf(g3, w.z, a3.z); a3.w = fmaf(g3, w.w, a3.w);
                        a4.x = fmaf(g4, w.x, a4.x); a4.y = fmaf(g4, w.y, a4.y);
                        a4.z = fmaf(g4, w.z, a4.z); a4.w = fmaf(g4, w.w, a4.w);
                        a5.x = fmaf(g5, w.x, a5.x); a5.y = fmaf(g5, w.y, a5.y);
                        a5.z = fmaf(g5, w.z, a5.z); a5.w = fmaf(g5, w.w, a5.w);
                        a6.x = fmaf(g6, w.x, a6.x); a6.y = fmaf(g6, w.y, a6.y);
                        a6.z = fmaf(g6, w.z, a6.z); a6.w = fmaf(g6, w.w, a6.w);
                        a7.x = fmaf(g7, w.x, a7.x); a7.y = fmaf(g7, w.y, a7.y);
                        a7.z = fmaf(g7, w.z, a7.z); a7.w = fmaf(g7, w.w, a7.w);
                    }
                }
                // write partials (named, unrolled -> no scratch)
                s_part[pbase + 0 * 8] = a0;
                s_part[pbase + 1 * 8] = a1;
                s_part[pbase + 2 * 8] = a2;
                s_part[pbase + 3 * 8] = a3;
                s_part[pbase + 4 * 8] = a4;
                s_part[pbase + 5 * 8] = a5;
                s_part[pbase + 6 * 8] = a6;
                s_part[pbase + 7 * 8] = a7;
            }
        } else if (owner && t > 0) {
            // ---- wave 4 of owner wg: o-LIF(t-1) + nbr(t-1), overlapped
            const int bufp = (t - 1) & 1;
            float ospsum = 0.0f;
#pragma unroll
            for (int p = 0; p < 3; ++p) {
                int idx = p * 64 + lane;
                if (idx < 160) {
                    const float* gp =
                        g_opart + bufp * 81920 + ((b0 + vb[p]) * 32) * O_ + vo[p];
                    float oin = s_bo[vo[p]];
#pragma unroll
                    for (int c = 0; c < 32; ++c)
                        oin += __hip_atomic_load(gp + c * O_, __ATOMIC_RELAXED,
                                                 __HIP_MEMORY_SCOPE_AGENT);
                    float om = s_om[idx] + oin;
                    float osp = ((om - s_tho[vo[p]]) > 0.0f) ? 1.0f : 0.0f;
                    if (osp > 0.5f) om = 0.0f;
                    if (om < -s_tho[vo[p]]) om = -s_tho[vo[p]];
                    s_om[idx] = om;
                    s_osum[idx] += osp;
                    ospsum += osp;
                }
            }
            int hid = 0;
#pragma unroll
            for (int k = 0; k < 4; ++k) hid += __popc(s_mask32[lane * 4 + k]);
            float tot = ospsum + (float)hid;
            tot += __shfl_xor(tot, 1);  tot += __shfl_xor(tot, 2);
            tot += __shfl_xor(tot, 4);  tot += __shfl_xor(tot, 8);
            tot += __shfl_xor(tot, 16); tot += __shfl_xor(tot, 32);
            if (lane == 0) atomicAdd(&nbr_acc[t - 1], tot);  // exact ints
        }
        __syncthreads();                       // S3

        if (full && tid < 256) {
            const int b = tid >> 5, hoff = tid & 31;
            const int cq = hoff >> 2, comp = hoff & 3;
            const float* sp = (const float*)s_part;
            float val = 0.0f;
#pragma unroll
            for (int w4 = 0; w4 < 4; ++w4)
#pragma unroll
                for (int r = 0; r < 8; ++r)
                    val += sp[((((w4 * 8 + r) * 8 + b) * 8) + cq) * 4 + comp];
            hm += xi + val;
            bool spb = (hm - thr) > 0.0f;      // strict >
            if (spb) hm = 0.0f;
            if (hm < -thr) hm = -thr;
            if (spb) { if (t < 64) bits0 |= 1ull << t; else bits1 |= 1ull << (t - 64); }

            unsigned long long bal = __ballot(spb);
            const int wb = tid >> 6;           // wave holds batches 2wb, 2wb+1
            const int buf = t & 1;
            if (lane == 0)
                __hip_atomic_store(g_mask32 + buf * 4096 + (b0 + wb * 2) * 32 + cg,
                                   (unsigned int)bal, __ATOMIC_RELAXED,
                                   __HIP_MEMORY_SCOPE_AGENT);
            if (lane == 32)
                __hip_atomic_store(g_mask32 + buf * 4096 + (b0 + wb * 2 + 1) * 32 + cg,
                                   (unsigned int)(bal >> 32), __ATOMIC_RELAXED,
                                   __HIP_MEMORY_SCOPE_AGENT);
            const int o = lane & 31;
            if (o < O_) {
                unsigned int mm = (lane < 32) ? (unsigned int)bal
                                              : (unsigned int)(bal >> 32);
                const int ob = b0 + wb * 2 + (lane >= 32 ? 1 : 0);
                float op = 0.0f;
                while (mm) {
                    int j = __builtin_ctz(mm);
                    mm &= mm - 1;
                    op += W2oT[(c0 + j) * O_ + o];
                }
                __hip_atomic_store(g_opart + buf * 81920 + (ob * 32 + cg) * O_ + o,
                                   op, __ATOMIC_RELAXED, __HIP_MEMORY_SCOPE_AGENT);
            }
        }
        __syncthreads();                       // S4
        if (full && tid == 0)
            __hip_atomic_fetch_add(g_cnt + bg, 1, __ATOMIC_RELEASE,
                                   __HIP_MEMORY_SCOPE_AGENT);
    }

    if (tid < 256) {
        int b = tid >> 5, hoff = tid & 31;
        ulonglong2 vv; vv.x = bits0; vv.y = bits1;
        spk[(size_t)(b0 + b) * H_ + c0 + hoff] = vv;
    }
    if (owner && tid < 160)
        osum_out[(b0 + tid / O_) * O_ + tid % O_] = s_osum[tid];
}

// ---------------------------------------------------------------------------
// sliding-window mean of spike bitmasks
// ---------------------------------------------------------------------------
__global__ __launch_bounds__(256) void filt_kernel(const ulonglong2* __restrict__ spk,
                                                   float* __restrict__ outf)
{
    int i = blockIdx.x * 256 + threadIdx.x;
    ulonglong2 v = spk[i];
    float* o = outf + (size_t)i * 91;
    int s = __popcll(v.x & 0x3FFull);
    o[0] = (float)s * 0.1f;
#pragma unroll 1
    for (int tau = 1; tau <= 90; ++tau) {
        int ta = tau + 9, tsb = tau - 1;
        int add = (ta < 64) ? (int)((v.x >> ta) & 1ull) : (int)((v.y >> (ta - 64)) & 1ull);
        int sub = (tsb < 64) ? (int)((v.x >> tsb) & 1ull) : (int)((v.y >> (tsb - 64)) & 1ull);
        s += add - sub;
        o[tau] = (float)s * 0.1f;
    }
}

// ---------------------------------------------------------------------------
// predictions / loss / nbr scaling
// ---------------------------------------------------------------------------
__global__ __launch_bounds__(256) void final_kernel(const float* __restrict__ osum,
                                                    const int* __restrict__ labels,
                                                    float* __restrict__ dout)
{
    __shared__ float s_loss[B_];
    int tid = threadIdx.x;
    if (tid < B_) {
        int b = tid;
        float v[O_];
#pragma unroll
        for (int o = 0; o < O_; ++o) v[o] = osum[b * O_ + o];
        float mv = v[0];
        int am = 0;
#pragma unroll
        for (int o = 1; o < O_; ++o)
            if (v[o] > mv) { mv = v[o]; am = o; }   // strict >: first max wins
        float se = 0.0f;
#pragma unroll
        for (int o = 0; o < O_; ++o) se += expf(v[o] - mv);
        float lse = mv + logf(se);
        dout[b] = (float)am;
        s_loss[b] = v[labels[b]] - lse;
    }
    if (tid >= 128 && tid < 128 + T_) {
        dout[129 + (tid - 128)] *= (1.0f / (float)B_);
    }
    __syncthreads();
    if (tid == 0) {
        float s = 0.0f;
        for (int b = 0; b < B_; ++b) s += s_loss[b];
        dout[128] = -s / (float)B_;
    }
}

// ---------------------------------------------------------------------------
extern "C" void kernel_launch(void* const* d_in, const int* in_sizes, int n_in,
                              void* d_out, int out_size, void* d_ws, size_t ws_size,
                              hipStream_t stream)
{
    const float* input  = (const float*)d_in[0];
    const int*   labels = (const int*)d_in[1];
    const float* hm0    = (const float*)d_in[2];
    const float* hs0    = (const float*)d_in[3];
    const float* om0    = (const float*)d_in[4];
    const float* Wi2h   = (const float*)d_in[6];
    const float* bi2h   = (const float*)d_in[7];
    const float* Wh2h   = (const float*)d_in[8];
    const float* bh2h   = (const float*)d_in[9];
    const float* Wh2o   = (const float*)d_in[10];
    const float* bh2o   = (const float*)d_in[11];
    const float* thr_h  = (const float*)d_in[12];
    const float* thr_o  = (const float*)d_in[13];

    float* out  = (float*)d_out;
    float* nbr  = out + 129;
    float* filt = out + 229;

    char* ws = (char*)d_ws;
    float*        Xi     = (float*)(ws);                 // 52,428,800
    float*        WT     = (float*)(ws + 52428800);      //  4,194,304
    float*        W2oT   = (float*)(ws + 56623104);      //     81,920
    ulonglong2*   spk    = (ulonglong2*)(ws + 56705024); //  2,097,152
    float*        osum   = (float*)(ws + 58802176);      //     10,240
    unsigned int* g_mask32 = (unsigned int*)(ws + 58812416); // 32,768
    float*        g_opart  = (float*)(ws + 58845184);    //    655,360
    int*          g_cnt    = (int*)(ws + 59500544);      //         64

    prep_kernel<<<80, 256, 0, stream>>>(Wh2o, W2oT, nbr, g_cnt);
    transpose_kernel<<<dim3(32, 32), dim3(32, 8), 0, stream>>>(Wh2h, WT);
    gemm_xi_kernel<<<dim3(100, 8), 256, 0, stream>>>(input, Wi2h, bi2h, bh2h, Xi);
    phase2_kernel<<<512, 320, 0, stream>>>(Xi, WT, W2oT, bh2o, thr_h, thr_o,
                                           hm0, hs0, om0, g_mask32, g_opart, g_cnt,
                                           spk, osum, nbr);
    filt_kernel<<<512, 256, 0, stream>>>(spk, filt);
    final_kernel<<<1, 256, 0, stream>>>(osum, labels, out);
}

// Round 7
// 2021.641 us; speedup vs baseline: 4.1485x; 2.9914x over previous
//
#include <hip/hip_runtime.h>
#include <hip/hip_bf16.h>
#include <cstdint>
#include <cstddef>

#define B_ 128
#define T_ 100
#define D_ 2048
#define H_ 1024
#define O_ 20
#define H2 512

__device__ inline void f4acc(float4& a, const float4 v) {
    a.x += v.x; a.y += v.y; a.z += v.z; a.w += v.w;
}

// ---------------------------------------------------------------------------
// prep: W2oT[h][o] = Wh2o[o][h]; zero nbr accumulators and pair flags.
// ---------------------------------------------------------------------------
__global__ __launch_bounds__(256) void prep_kernel(const float* __restrict__ Wh2o,
                                                   float* __restrict__ W2oT,
                                                   float* __restrict__ nbr,
                                                   int* __restrict__ g_flag)
{
    int i = blockIdx.x * 256 + threadIdx.x;
    if (i < H_ * O_) {
        int hh = i / O_;
        int oo = i - hh * O_;
        W2oT[i] = Wh2o[oo * H_ + hh];
    }
    if (i < T_) nbr[i] = 0.0f;
    if (i < B_ * 2) g_flag[i] = 0;
}

// ---------------------------------------------------------------------------
// transpose Wh2h[h][j] -> WT[j][h]
// ---------------------------------------------------------------------------
__global__ __launch_bounds__(256) void transpose_kernel(const float* __restrict__ A,
                                                        float* __restrict__ AT)
{
    __shared__ float tile[32][33];
    int bx = blockIdx.x * 32, by = blockIdx.y * 32;
    int tx = threadIdx.x, ty = threadIdx.y;  // block (32,8)
#pragma unroll
    for (int i = 0; i < 32; i += 8)
        tile[ty + i][tx] = A[(size_t)(by + ty + i) * H_ + bx + tx];
    __syncthreads();
#pragma unroll
    for (int i = 0; i < 32; i += 8)
        AT[(size_t)(bx + ty + i) * H_ + by + tx] = tile[tx][ty + i];
}

// ---------------------------------------------------------------------------
// Xi = X @ Wi2h^T + (bi2h + bh2h).  128x128x16 tile, 256 threads, 8x8 micro.
// ---------------------------------------------------------------------------
__global__ __launch_bounds__(256) void gemm_xi_kernel(
    const float* __restrict__ X,     // [B*T, D]
    const float* __restrict__ W,     // [H, D]
    const float* __restrict__ bi2h,
    const float* __restrict__ bh2h,
    float* __restrict__ Xi)          // [B*T, H]
{
    constexpr int BM = 128, BN = 128, BK = 16;
    __shared__ float As[BK][BM + 4];
    __shared__ float Bs[BK][BN + 4];
    const int tid = threadIdx.x;
    const int m0 = blockIdx.x * BM;
    const int n0 = blockIdx.y * BN;
    const int wave = tid >> 6;
    const int lane = tid & 63;
    const int tm = ((wave >> 1) << 3) | (lane >> 3);   // 0..15
    const int tn = ((wave & 1) << 3) | (lane & 7);     // 0..15
    const int ldr = tid >> 2;          // 0..63
    const int ldc = (tid & 3) << 2;    // 0,4,8,12

    float acc[8][8];
#pragma unroll
    for (int i = 0; i < 8; ++i)
#pragma unroll
        for (int j = 0; j < 8; ++j) acc[i][j] = 0.0f;

    for (int k0 = 0; k0 < D_; k0 += BK) {
#pragma unroll
        for (int p = 0; p < 2; ++p) {
            int r = ldr + p * 64;
            float4 v = *(const float4*)(X + (size_t)(m0 + r) * D_ + k0 + ldc);
            As[ldc + 0][r] = v.x; As[ldc + 1][r] = v.y;
            As[ldc + 2][r] = v.z; As[ldc + 3][r] = v.w;
        }
#pragma unroll
        for (int p = 0; p < 2; ++p) {
            int r = ldr + p * 64;
            float4 v = *(const float4*)(W + (size_t)(n0 + r) * D_ + k0 + ldc);
            Bs[ldc + 0][r] = v.x; Bs[ldc + 1][r] = v.y;
            Bs[ldc + 2][r] = v.z; Bs[ldc + 3][r] = v.w;
        }
        __syncthreads();
#pragma unroll
        for (int k = 0; k < BK; ++k) {
            float4 A0 = *(const float4*)&As[k][tm * 8];
            float4 A1 = *(const float4*)&As[k][tm * 8 + 4];
            float4 B0 = *(const float4*)&Bs[k][tn * 8];
            float4 B1 = *(const float4*)&Bs[k][tn * 8 + 4];
            float a[8] = {A0.x, A0.y, A0.z, A0.w, A1.x, A1.y, A1.z, A1.w};
            float bb[8] = {B0.x, B0.y, B0.z, B0.w, B1.x, B1.y, B1.z, B1.w};
#pragma unroll
            for (int i = 0; i < 8; ++i)
#pragma unroll
                for (int j = 0; j < 8; ++j) acc[i][j] += a[i] * bb[j];
        }
        __syncthreads();
    }

    float bsum[8];
#pragma unroll
    for (int j = 0; j < 8; ++j) {
        int n = n0 + tn * 8 + j;
        bsum[j] = bi2h[n] + bh2h[n];
    }
#pragma unroll
    for (int i = 0; i < 8; ++i) {
        size_t row = (size_t)(m0 + tm * 8 + i);
        float4 o0 = {acc[i][0] + bsum[0], acc[i][1] + bsum[1],
                     acc[i][2] + bsum[2], acc[i][3] + bsum[3]};
        float4 o1 = {acc[i][4] + bsum[4], acc[i][5] + bsum[5],
                     acc[i][6] + bsum[6], acc[i][7] + bsum[7]};
        *(float4*)(Xi + row * H_ + n0 + tn * 8)     = o0;
        *(float4*)(Xi + row * H_ + n0 + tn * 8 + 4) = o1;
    }
}

// ---------------------------------------------------------------------------
// phase2 v7 = R3's overlapped control flow + R2's XCD placement.
// pair = blk>>1, half = blk&1  =>  XCD k (blk%8) hosts ONLY column-half k&1:
// per-XCD WT working set = 2 MB (R2-proven FETCH ~40 MB; R3's 4 MB/XCD
// placement thrashed to 178 MB — the ONLY thing R3 got wrong).
// Per step: gather own-half active rows FIRST (hides partner publish
// latency), then spin for partner mask(t-1), gather partner rows.
// o-layer one step behind on half 0 (single wait per step). Loop to t=T:
// iteration T does the final o-step/nbr for t=99.
// ---------------------------------------------------------------------------
__global__ __launch_bounds__(512) void phase2_kernel(
    const float* __restrict__ Xi,      // [B*T, H]
    const float* __restrict__ WT,      // [j*H + h]
    const float* __restrict__ W2oT,    // [h*O + o]
    const float* __restrict__ bh2o,
    const float* __restrict__ thr_h_g,
    const float* __restrict__ thr_o_g,
    const float* __restrict__ hm0,
    const float* __restrict__ hs0,
    const float* __restrict__ om0,
    unsigned long long* __restrict__ g_mask,   // [B][2 buf][2 half][8]
    int* __restrict__ g_flag,                  // [B][2 half]
    ulonglong2* __restrict__ spk,              // [B*H]
    float* __restrict__ osum_out,              // [B,O]
    float* __restrict__ nbr_acc)               // [T] pre-zeroed
{
    const int pair = blockIdx.x >> 1;   // R2 placement: adjacent blocks pair up
    const int half = blockIdx.x & 1;    // XCD k hosts only half k&1
    const int b = pair;
    const int tid = threadIdx.x;
    const int lane = tid & 63;
    const int wv = tid >> 6;            // 0..7
    const int h0 = half * H2;
    const int ph0 = h0 ^ H2;
    const int h = h0 + tid;

    __shared__ int   s_list[1024];              // [0,512) own, [512,1024) partner
    __shared__ float4 s_red[4][128];
    __shared__ unsigned long long s_mask[16];   // global word order
    __shared__ float s_opart[8][O_];
    __shared__ float s_om[O_], s_osum[O_], s_tho[O_], s_bo[O_];

    float hm = hm0[(size_t)b * H_ + h];
    const float thr = thr_h_g[h];

    if (half == 0 && tid < O_) {
        s_om[tid]   = om0[b * O_ + tid];
        s_osum[tid] = 0.0f;
        s_tho[tid]  = thr_o_g[tid];
        s_bo[tid]   = bh2o[tid];
    }

    // initial mask(-1) from hs0 — both halves computed locally, no exchange
    {
        bool own = hs0[(size_t)b * H_ + h] > 0.5f;
        bool par = hs0[(size_t)b * H_ + ph0 + tid] > 0.5f;
        unsigned long long mo = __ballot(own), mp = __ballot(par);
        if (lane == 0) { s_mask[half * 8 + wv] = mo; s_mask[(half ^ 1) * 8 + wv] = mp; }
    }
    __syncthreads();

    int cnt_own;
    {   // own list (region A) — redundant per-thread prefix, no extra barrier
        const int ow = half * 8;
        int pc[8];
#pragma unroll
        for (int k = 0; k < 8; ++k) pc[k] = __popcll(s_mask[ow + k]);
        int basew = 0, tot = 0;
#pragma unroll
        for (int k = 0; k < 8; ++k) { if (k < wv) basew += pc[k]; tot += pc[k]; }
        cnt_own = tot;
        unsigned long long mw = s_mask[ow + wv];
        if ((mw >> lane) & 1ull)
            s_list[basew + __popcll(mw & ((1ull << lane) - 1ull))] = h;
    }
    __syncthreads();

    const float4* __restrict__ wt4b = (const float4*)WT + (h0 >> 2); // + j*256 + cid
    const int g = tid >> 7;          // list group 0..3
    const int cid = tid & 127;       // float4 column within half
    const int fl_partner = pair * 2 + (half ^ 1);
    const int fl_self    = pair * 2 + half;
    unsigned long long bits0 = 0, bits1 = 0;

    for (int t = 0; t <= T_; ++t) {
        const bool full = (t < T_);
        float xi = 0.0f;
        if (full) xi = Xi[((size_t)b * T_ + t) * H_ + h];

        float4 c0 = {0,0,0,0}, c1 = {0,0,0,0}, c2 = {0,0,0,0}, c3 = {0,0,0,0};
        float4 c4 = {0,0,0,0}, c5 = {0,0,0,0}, c6 = {0,0,0,0}, c7 = {0,0,0,0};

        // ---- phase 1: own-half active rows (no partner dependency) ----
        if (full) {
            const int c = cnt_own;
            int l = g;
            for (; l + 28 < c; l += 32) {
                int j0 = s_list[l],      j1 = s_list[l + 4];
                int j2 = s_list[l + 8],  j3 = s_list[l + 12];
                int j4 = s_list[l + 16], j5 = s_list[l + 20];
                int j6 = s_list[l + 24], j7 = s_list[l + 28];
                f4acc(c0, wt4b[(size_t)j0 * 256 + cid]);
                f4acc(c1, wt4b[(size_t)j1 * 256 + cid]);
                f4acc(c2, wt4b[(size_t)j2 * 256 + cid]);
                f4acc(c3, wt4b[(size_t)j3 * 256 + cid]);
                f4acc(c4, wt4b[(size_t)j4 * 256 + cid]);
                f4acc(c5, wt4b[(size_t)j5 * 256 + cid]);
                f4acc(c6, wt4b[(size_t)j6 * 256 + cid]);
                f4acc(c7, wt4b[(size_t)j7 * 256 + cid]);
            }
            for (; l < c; l += 4) f4acc(c0, wt4b[(size_t)s_list[l] * 256 + cid]);
        }

        // ---- spin for partner mask(t-1) — latency hidden by phase 1 ----
        if (t > 0 && tid == 0) {
            while (__hip_atomic_load(&g_flag[fl_partner], __ATOMIC_ACQUIRE,
                                     __HIP_MEMORY_SCOPE_AGENT) < t)
                __builtin_amdgcn_s_sleep(1);
        }
        __syncthreads();                            // B1
        if (t > 0 && tid < 8) {
            const unsigned long long* pm =
                g_mask + (((size_t)(pair * 2 + ((t - 1) & 1)) * 2 + (half ^ 1)) * 8);
            s_mask[(half ^ 1) * 8 + tid] =
                __hip_atomic_load(&pm[tid], __ATOMIC_RELAXED, __HIP_MEMORY_SCOPE_AGENT);
        }
        __syncthreads();                            // B2

        int cnt_p;
        {   // partner list (region B) — redundant prefix
            const int pw = (half ^ 1) * 8;
            int pc[8];
#pragma unroll
            for (int k = 0; k < 8; ++k) pc[k] = __popcll(s_mask[pw + k]);
            int basew = 0, tot = 0;
#pragma unroll
            for (int k = 0; k < 8; ++k) { if (k < wv) basew += pc[k]; tot += pc[k]; }
            cnt_p = tot;
            unsigned long long mw = s_mask[pw + wv];
            if ((mw >> lane) & 1ull)
                s_list[512 + basew + __popcll(mw & ((1ull << lane) - 1ull))] =
                    ph0 + wv * 64 + lane;
        }
        __syncthreads();                            // B3

        // ---- phase 2: partner-half active rows ----
        if (full) {
            const int c = cnt_p;
            int l = g;
            for (; l + 28 < c; l += 32) {
                int j0 = s_list[512 + l],      j1 = s_list[512 + l + 4];
                int j2 = s_list[512 + l + 8],  j3 = s_list[512 + l + 12];
                int j4 = s_list[512 + l + 16], j5 = s_list[512 + l + 20];
                int j6 = s_list[512 + l + 24], j7 = s_list[512 + l + 28];
                f4acc(c0, wt4b[(size_t)j0 * 256 + cid]);
                f4acc(c1, wt4b[(size_t)j1 * 256 + cid]);
                f4acc(c2, wt4b[(size_t)j2 * 256 + cid]);
                f4acc(c3, wt4b[(size_t)j3 * 256 + cid]);
                f4acc(c4, wt4b[(size_t)j4 * 256 + cid]);
                f4acc(c5, wt4b[(size_t)j5 * 256 + cid]);
                f4acc(c6, wt4b[(size_t)j6 * 256 + cid]);
                f4acc(c7, wt4b[(size_t)j7 * 256 + cid]);
            }
            for (; l < c; l += 4) f4acc(c0, wt4b[(size_t)s_list[512 + l] * 256 + cid]);
        }

        // ---- o-layer partials for step t-1 (half0 only; L2 W2oT reads) ----
        if (half == 0 && t > 0 && lane < O_) {
            float op = 0.0f;
            for (int q = wv; q < cnt_own; q += 8) op += W2oT[s_list[q] * O_ + lane];
            for (int q = wv; q < cnt_p; q += 8)  op += W2oT[s_list[512 + q] * O_ + lane];
            s_opart[wv][lane] = op;
        }

        {   // combine chains -> s_red
            f4acc(c0, c1); f4acc(c2, c3); f4acc(c4, c5); f4acc(c6, c7);
            f4acc(c0, c2); f4acc(c4, c6); f4acc(c0, c4);
            s_red[g][cid] = c0;
        }
        const int hidprev = cnt_own + cnt_p;        // popcount of mask(t-1)
        __syncthreads();                            // B4

        if (full) {
            const float* rf = (const float*)s_red;
            float val = rf[tid] + rf[512 + tid] + rf[1024 + tid] + rf[1536 + tid];
            hm += xi + val;
            bool sp = (hm - thr) > 0.0f;
            if (sp) hm = 0.0f;
            if (hm < -thr) hm = -thr;
            if (sp) { if (t < 64) bits0 |= 1ull << t; else bits1 |= 1ull << (t - 64); }
            unsigned long long m = __ballot(sp);
            if (lane == 0) {
                s_mask[half * 8 + wv] = m;
                unsigned long long* gm =
                    g_mask + (((size_t)(pair * 2 + (t & 1)) * 2 + half) * 8);
                __hip_atomic_store(&gm[wv], m, __ATOMIC_RELAXED,
                                   __HIP_MEMORY_SCOPE_AGENT);
            }
        }

        // ---- o-LIF(t-1) + nbr(t-1): half0 ----
        if (half == 0 && t > 0) {
            float osp_l = 0.0f;
            if (tid < O_) {
                float oin = s_bo[tid];
#pragma unroll
                for (int w = 0; w < 8; ++w) oin += s_opart[w][tid];
                float om = s_om[tid] + oin;
                float osp = ((om - s_tho[tid]) > 0.0f) ? 1.0f : 0.0f;
                if (osp > 0.5f) om = 0.0f;
                if (om < -s_tho[tid]) om = -s_tho[tid];
                s_om[tid] = om;
                s_osum[tid] += osp;
                osp_l = osp;
            }
            if (wv == 0) {
                float cc = osp_l;
                cc += __shfl_xor(cc, 1);  cc += __shfl_xor(cc, 2);
                cc += __shfl_xor(cc, 4);  cc += __shfl_xor(cc, 8);
                cc += __shfl_xor(cc, 16); cc += __shfl_xor(cc, 32);
                if (lane == 0)
                    atomicAdd(&nbr_acc[t - 1], cc + (float)hidprev); // exact ints
            }
        }
        __syncthreads();                            // B5
        if (full && tid == 0)
            __hip_atomic_store(&g_flag[fl_self], t + 1, __ATOMIC_RELEASE,
                               __HIP_MEMORY_SCOPE_AGENT);
        if (full) {   // rebuild own list (region A) for next iteration
            const int ow = half * 8;
            int pc[8];
#pragma unroll
            for (int k = 0; k < 8; ++k) pc[k] = __popcll(s_mask[ow + k]);
            int basew = 0, tot = 0;
#pragma unroll
            for (int k = 0; k < 8; ++k) { if (k < wv) basew += pc[k]; tot += pc[k]; }
            cnt_own = tot;
            unsigned long long mw = s_mask[ow + wv];
            if ((mw >> lane) & 1ull)
                s_list[basew + __popcll(mw & ((1ull << lane) - 1ull))] = h;
        }
        __syncthreads();                            // B6
    }

    ulonglong2 vv; vv.x = bits0; vv.y = bits1;
    spk[(size_t)b * H_ + h] = vv;
    if (half == 0 && tid < O_) osum_out[b * O_ + tid] = s_osum[tid];
}

// ---------------------------------------------------------------------------
// sliding-window mean of spike bitmasks
// ---------------------------------------------------------------------------
__global__ __launch_bounds__(256) void filt_kernel(const ulonglong2* __restrict__ spk,
                                                   float* __restrict__ outf)
{
    int i = blockIdx.x * 256 + threadIdx.x;
    ulonglong2 v = spk[i];
    float* o = outf + (size_t)i * 91;
    int s = __popcll(v.x & 0x3FFull);
    o[0] = (float)s * 0.1f;
#pragma unroll 1
    for (int tau = 1; tau <= 90; ++tau) {
        int ta = tau + 9, tsb = tau - 1;
        int add = (ta < 64) ? (int)((v.x >> ta) & 1ull) : (int)((v.y >> (ta - 64)) & 1ull);
        int sub = (tsb < 64) ? (int)((v.x >> tsb) & 1ull) : (int)((v.y >> (tsb - 64)) & 1ull);
        s += add - sub;
        o[tau] = (float)s * 0.1f;
    }
}

// ---------------------------------------------------------------------------
// predictions / loss / nbr scaling
// ---------------------------------------------------------------------------
__global__ __launch_bounds__(256) void final_kernel(const float* __restrict__ osum,
                                                    const int* __restrict__ labels,
                                                    float* __restrict__ dout)
{
    __shared__ float s_loss[B_];
    int tid = threadIdx.x;
    if (tid < B_) {
        int b = tid;
        float v[O_];
#pragma unroll
        for (int o = 0; o < O_; ++o) v[o] = osum[b * O_ + o];
        float mv = v[0];
        int am = 0;
#pragma unroll
        for (int o = 1; o < O_; ++o)
            if (v[o] > mv) { mv = v[o]; am = o; }   // strict >: first max wins
        float se = 0.0f;
#pragma unroll
        for (int o = 0; o < O_; ++o) se += expf(v[o] - mv);
        float lse = mv + logf(se);
        dout[b] = (float)am;
        s_loss[b] = v[labels[b]] - lse;
    }
    if (tid >= 128 && tid < 128 + T_) {
        dout[129 + (tid - 128)] *= (1.0f / (float)B_);
    }
    __syncthreads();
    if (tid == 0) {
        float s = 0.0f;
        for (int b = 0; b < B_; ++b) s += s_loss[b];
        dout[128] = -s / (float)B_;
    }
}

// ---------------------------------------------------------------------------
extern "C" void kernel_launch(void* const* d_in, const int* in_sizes, int n_in,
                              void* d_out, int out_size, void* d_ws, size_t ws_size,
                              hipStream_t stream)
{
    const float* input  = (const float*)d_in[0];
    const int*   labels = (const int*)d_in[1];
    const float* hm0    = (const float*)d_in[2];
    const float* hs0    = (const float*)d_in[3];
    const float* om0    = (const float*)d_in[4];
    const float* Wi2h   = (const float*)d_in[6];
    const float* bi2h   = (const float*)d_in[7];
    const float* Wh2h   = (const float*)d_in[8];
    const float* bh2h   = (const float*)d_in[9];
    const float* Wh2o   = (const float*)d_in[10];
    const float* bh2o   = (const float*)d_in[11];
    const float* thr_h  = (const float*)d_in[12];
    const float* thr_o  = (const float*)d_in[13];

    float* out  = (float*)d_out;
    float* nbr  = out + 129;
    float* filt = out + 229;

    char* ws = (char*)d_ws;
    float*      Xi     = (float*)(ws);                   // 52,428,800
    float*      WT     = (float*)(ws + 52428800);        //  4,194,304
    float*      W2oT   = (float*)(ws + 56623104);        //     81,920
    ulonglong2* spk    = (ulonglong2*)(ws + 56705024);   //  2,097,152
    float*      osum   = (float*)(ws + 58802176);        //     10,240
    unsigned long long* g_mask = (unsigned long long*)(ws + 58812416); // 32,768
    int*        g_flag  = (int*)(ws + 58845184);         //      1,024

    prep_kernel<<<80, 256, 0, stream>>>(Wh2o, W2oT, nbr, g_flag);
    transpose_kernel<<<dim3(32, 32), dim3(32, 8), 0, stream>>>(Wh2h, WT);
    gemm_xi_kernel<<<dim3(100, 8), 256, 0, stream>>>(input, Wi2h, bi2h, bh2h, Xi);
    phase2_kernel<<<256, 512, 0, stream>>>(Xi, WT, W2oT, bh2o, thr_h, thr_o,
                                           hm0, hs0, om0, g_mask, g_flag,
                                           spk, osum, nbr);
    filt_kernel<<<512, 256, 0, stream>>>(spk, filt);
    final_kernel<<<1, 256, 0, stream>>>(osum, labels, out);
}